// Round 17
// baseline (31.487 us; speedup 1.0000x reference)
//
#include <hip/hip_runtime.h>
#include <hip/hip_bf16.h>

// R28 = R27 (verified champion, 31.43us) + overlapped-prologue staging.
// R27's prologue serialized TWO global round-trips per block: load(0) ->
// store(0) [vmcnt drain] -> load(1) -> store(1) [vmcnt drain] (~1200-1800cyc,
// run by every wave before the first barrier). Fix: dual prologue-only
// staging register set -- issue BOTH tiles' loads back-to-back, then convert/
// store each as it lands (compiler emits counted vmcnt: first store waits
// only on set A, set B stays in flight). VGPR 64 -> ~80, still well under the
// 128-reg budget for 4 waves/SIMD -> occupancy unchanged. Loop body, buffer
// discipline, arithmetic all R27-verbatim -> output bit-identical.
// Pre-committed read: >=31.2us (neutral) means the chain-trim lever class is
// exhausted and the next round declares the plateau.
// Ledger: chain-trims R21/R26/R27 = -0.5/-0.7/-0.9us; structural probes
// R17/R18/R19/R24 all regressed; micro bundles R20/R22/R23 neutral-negative.

#define NB    64
#define LQ    1024
#define LK    1024
#define DH    64
#define KVT   64
#define QT    128
#define NITEMS (NB * (LQ / QT))      // 512
#define NEGF  1.0e30f
#define SC2   0.18033688011112042f   // 0.125 * log2(e)
#define THR   8.0f                   // defer-max threshold (log2 units)

typedef __attribute__((ext_vector_type(8))) short    bf8;
typedef __attribute__((ext_vector_type(8))) ushort   u16x8;
typedef __attribute__((ext_vector_type(4))) ushort   u16x4;
typedef __attribute__((ext_vector_type(4))) float    f4;

__device__ __forceinline__ ushort2 cvt2(float a, float b) {   // v_cvt_pk_bf16_f32
    float2 f; f.x = a; f.y = b;
    __hip_bfloat162 h = __float22bfloat162_rn(f);
    union { __hip_bfloat162 h2; ushort2 u2; } u;
    u.h2 = h;
    return u.u2;
}
__device__ __forceinline__ int swz16(int row, int colbyte) {  // K, V^T tiles
    return row * 128 + ((((colbyte >> 4) ^ (row & 7)) << 4) | (colbyte & 15));
}
__device__ __forceinline__ float fm3(float a, float b, float c) {  // v_max3
    return fmaxf(fmaxf(a, b), c);
}

__global__ __launch_bounds__(512, 4)
void attn_v28(const float* __restrict__ Q, const float* __restrict__ K,
              const float* __restrict__ V, const int* __restrict__ VL,
              float* __restrict__ O) {
    __shared__ ushort KsB[4][KVT * DH];   // swz16 [phys key][d] 32 KB
    __shared__ ushort VtB[4][DH * KVT];   // swz16 [d][key]      32 KB
    __shared__ ushort sched[NB];          // rank -> batch        128 B => 65664

    const int tid = threadIdx.x;
    const int wid = tid >> 6, l = tid & 63, g = l >> 4, a = l & 15;

    // ---- in-kernel stratified-LPT schedule ----
    if (tid < NB) {
        const int ntb = (VL[tid] + KVT - 1) >> 6;
        int r = 0;
        for (int j = 0; j < NB; ++j) {
            const int ntj = (VL[j] + KVT - 1) >> 6;
            r += (int)((ntj > ntb) | ((ntj == ntb) & (j < tid)));
        }
        sched[r] = (ushort)tid;           // rank -> batch (desc nt, tie asc)
    }
    __syncthreads();
    const int xcd   = blockIdx.x & 7;     // HW: block i -> XCD i%8
    const int slot  = blockIdx.x >> 3;    // 0..63 within XCD
    const int qtile = slot & 7;           // 8 q-slots of 128 rows
    const int st    = slot >> 3;          // stratum 0..7
    // pairing perm8={0,1,2,3,7,6,5,4}: CU gets complementary strata
    const int rank  = xcd + ((st < 4) ? st : (11 - st)) * 8;
    const int b     = sched[rank];
    const int qbase = qtile * QT;
    const int valid = VL[b];              // 1..1024
    const int nt = (valid + KVT - 1) >> 6;

    // Hoisted LDS read offsets: same formula serves K and V reads.
    int off8[8];                          // [n][kblk] -> n*2 + kblk
    #pragma unroll
    for (int n = 0; n < 4; ++n)
        #pragma unroll
        for (int kblk = 0; kblk < 2; ++kblk)
            off8[n * 2 + kblk] = swz16(n * 16 + a, kblk * 64 + g * 16);

    // Q fragment (B-operand), pre-scaled by SC2: col=a (q-row), k=32kblk+8g+i
    const float* Qr = Q + ((size_t)b * LQ + qbase + wid * 16 + a) * DH;
    bf8 qa[2];
    #pragma unroll
    for (int kblk = 0; kblk < 2; ++kblk) {
        f4 x = *(const f4*)(Qr + kblk * 32 + g * 8);
        f4 y = *(const f4*)(Qr + kblk * 32 + g * 8 + 4);
        ushort2 c0 = cvt2(x[0] * SC2, x[1] * SC2), c1 = cvt2(x[2] * SC2, x[3] * SC2);
        ushort2 c2 = cvt2(y[0] * SC2, y[1] * SC2), c3 = cvt2(y[2] * SC2, y[3] * SC2);
        qa[kblk][0] = (short)c0.x; qa[kblk][1] = (short)c0.y;
        qa[kblk][2] = (short)c1.x; qa[kblk][3] = (short)c1.y;
        qa[kblk][4] = (short)c2.x; qa[kblk][5] = (short)c2.y;
        qa[kblk][6] = (short)c3.x; qa[kblk][7] = (short)c3.y;
    }
    const bf8 ones = {0x3F80, 0x3F80, 0x3F80, 0x3F80,
                      0x3F80, 0x3F80, 0x3F80, 0x3F80};   // bf16 1.0 x8

    // staging roles: waves 0-3 stage V, waves 4-7 stage K (R16 split)
    const int  rtid  = tid & 255;
    const bool vrole = (wid < 4);
    const int srow = rtid >> 3, sslot = rtid & 7;   // K rows srow, srow+32
    const int vkp  = rtid >> 4, vj = rtid & 15;     // V keys 4vkp.., f4-col vj
    // physical LDS row for K key srow (<32): swap bits 3..4 with bit 2
    const int prow = (srow & 3) | ((srow & 24) >> 1) | ((srow & 4) << 2);
    const f4* Kb4 = (const f4*)(K + (size_t)b * LK * DH);
    const f4* Vb4 = (const f4*)(V + (size_t)b * LK * DH);

    f4 r0, r1, r2, r3;
    auto load_kv = [&](int k0) {
        if (vrole) {
            r0 = Vb4[(k0 + 4 * vkp + 0) * 16 + vj];
            r1 = Vb4[(k0 + 4 * vkp + 1) * 16 + vj];
            r2 = Vb4[(k0 + 4 * vkp + 2) * 16 + vj];
            r3 = Vb4[(k0 + 4 * vkp + 3) * 16 + vj];
        } else {
            r0 = Kb4[(k0 + srow) * 16 + sslot * 2];
            r1 = Kb4[(k0 + srow) * 16 + sslot * 2 + 1];
            r2 = Kb4[(k0 + srow + 32) * 16 + sslot * 2];
            r3 = Kb4[(k0 + srow + 32) * 16 + sslot * 2 + 1];
        }
    };
    auto store_from = [&](const int bs, f4 a0, f4 a1, f4 a2, f4 a3) {
        if (vrole) {
            char* vd = (char*)&VtB[bs][0];
            #pragma unroll
            for (int c = 0; c < 4; ++c) {      // transpose: d = 4*vj+c
                ushort2 a01 = cvt2(a0[c], a1[c]), a23 = cvt2(a2[c], a3[c]);
                u16x4 p = {a01.x, a01.y, a23.x, a23.y};
                *(u16x4*)(vd + swz16(4 * vj + c, vkp * 8)) = p;
            }
        } else {
            char* kd = (char*)&KsB[bs][0];
            {
                ushort2 c0 = cvt2(a0[0], a0[1]), c1 = cvt2(a0[2], a0[3]);
                ushort2 c2 = cvt2(a1[0], a1[1]), c3 = cvt2(a1[2], a1[3]);
                u16x8 w = {c0.x, c0.y, c1.x, c1.y, c2.x, c2.y, c3.x, c3.y};
                *(u16x8*)(kd + swz16(prow, sslot * 16)) = w;
            }
            {
                ushort2 c0 = cvt2(a2[0], a2[1]), c1 = cvt2(a2[2], a2[3]);
                ushort2 c2 = cvt2(a3[0], a3[1]), c3 = cvt2(a3[2], a3[3]);
                u16x8 w = {c0.x, c0.y, c1.x, c1.y, c2.x, c2.y, c3.x, c3.y};
                *(u16x8*)(kd + swz16(prow + 32, sslot * 16)) = w;
            }
        }
    };
    auto store_kv = [&](const int bs) { store_from(bs, r0, r1, r2, r3); };

    f4 oacc[4];
    #pragma unroll
    for (int n = 0; n < 4; ++n) oacc[n] = f4{0.f, 0.f, 0.f, 0.f};
    f4 lacc = f4{0.f, 0.f, 0.f, 0.f};   // l per q-row 4g+r (epilogue layout)
    float m_run = -NEGF;                // per-lane: q-row = a (row-uniform)

    // Pure compute for one tile; bs literal -> LDS bases fold into ds imms.
    auto compute_tile = [&](int t, const int bs) {
        // ---- S^T = K Q^T: lane (g,a) holds S[q=a][key=32(n>>1)+4(n&1)+8g+r]
        const char* kd = (const char*)&KsB[bs][0];
        f4 sacc[4];
        #pragma unroll
        for (int n = 0; n < 4; ++n) sacc[n] = f4{0.f, 0.f, 0.f, 0.f};
        __builtin_amdgcn_s_setprio(1);
        #pragma unroll
        for (int n = 0; n < 4; ++n)
            #pragma unroll
            for (int kblk = 0; kblk < 2; ++kblk) {
                bf8 kb = *(const bf8*)(kd + off8[n * 2 + kblk]);
                sacc[n] = __builtin_amdgcn_mfma_f32_16x16x32_bf16(
                    kb, qa[kblk], sacc[n], 0, 0, 0);   // A=K, B=Q
            }
        __builtin_amdgcn_s_setprio(0);

        // ---- mask in place ----
        const int kmax = valid - t * KVT;
        if (kmax < KVT) {
            #pragma unroll
            for (int n = 0; n < 4; ++n)
                #pragma unroll
                for (int r = 0; r < 4; ++r)
                    if (32 * (n >> 1) + 4 * (n & 1) + 8 * g + r >= kmax)
                        sacc[n][r] = -NEGF;
        }

        // ---- lane-local max: 3-ary tree (v_max3), no cross-lane ----
        float t0 = fm3(sacc[0][0], sacc[0][1], sacc[0][2]);
        float t1 = fm3(sacc[0][3], sacc[1][0], sacc[1][1]);
        float t2 = fm3(sacc[1][2], sacc[1][3], sacc[2][0]);
        float t3 = fm3(sacc[2][1], sacc[2][2], sacc[2][3]);
        float t4 = fm3(sacc[3][0], sacc[3][1], sacc[3][2]);
        float tm = fm3(fm3(t0, t1, t2), fm3(t3, t4, sacc[3][3]),
                       -NEGF);

        // ---- defer-max vote on lane-local max (== row-max vote) ----
        const bool skip = __all(tm <= m_run + THR);
        if (!skip) {
            tm = fmaxf(tm, __shfl_xor(tm, 16));   // row max (rare path)
            tm = fmaxf(tm, __shfl_xor(tm, 32));
            const float mnew = fmaxf(m_run, tm);
            const float rs_ = __builtin_exp2f(m_run - mnew);  // tile0: 0
            m_run = mnew;
            float rr[4];
            #pragma unroll
            for (int r = 0; r < 4; ++r) rr[r] = __shfl(rs_, 4 * g + r);
            #pragma unroll
            for (int n = 0; n < 4; ++n)
                #pragma unroll
                for (int r = 0; r < 4; ++r) oacc[n][r] *= rr[r];
            #pragma unroll
            for (int r = 0; r < 4; ++r) lacc[r] *= rr[r];
        }

        float p[4][4];
        #pragma unroll
        for (int n = 0; n < 4; ++n)
            #pragma unroll
            for (int r = 0; r < 4; ++r)
                p[n][r] = __builtin_exp2f(sacc[n][r] - m_run);   // masked -> 0

        // ---- O += P V ; l += P * ones  (P in registers; vb one b128) ----
        const char* vd = (const char*)&VtB[bs][0];
        __builtin_amdgcn_s_setprio(1);
        #pragma unroll
        for (int kblk = 0; kblk < 2; ++kblk) {
            ushort2 w0 = cvt2(p[2 * kblk][0], p[2 * kblk][1]);
            ushort2 w1 = cvt2(p[2 * kblk][2], p[2 * kblk][3]);
            ushort2 w2 = cvt2(p[2 * kblk + 1][0], p[2 * kblk + 1][1]);
            ushort2 w3 = cvt2(p[2 * kblk + 1][2], p[2 * kblk + 1][3]);
            bf8 pa = {(short)w0.x, (short)w0.y, (short)w1.x, (short)w1.y,
                      (short)w2.x, (short)w2.y, (short)w3.x, (short)w3.y};
            #pragma unroll
            for (int n = 0; n < 4; ++n) {
                bf8 vb_ = *(const bf8*)(vd + off8[n * 2 + kblk]);
                oacc[n] = __builtin_amdgcn_mfma_f32_16x16x32_bf16(
                    pa, vb_, oacc[n], 0, 0, 0);
            }
            lacc = __builtin_amdgcn_mfma_f32_16x16x32_bf16(pa, ones, lacc, 0, 0, 0);
        }
        __builtin_amdgcn_s_setprio(0);
    };

    // ---- prologue: BOTH tiles' loads in flight, then store each as it
    //      lands (counted vmcnt: store(0) waits only on set A) ----
    load_kv(0);                            // set A (r0..r3) in flight
    f4 s1_0, s1_1, s1_2, s1_3;             // set B (prologue-only regs)
    if (nt > 1) {
        if (vrole) {
            s1_0 = Vb4[(KVT + 4 * vkp + 0) * 16 + vj];
            s1_1 = Vb4[(KVT + 4 * vkp + 1) * 16 + vj];
            s1_2 = Vb4[(KVT + 4 * vkp + 2) * 16 + vj];
            s1_3 = Vb4[(KVT + 4 * vkp + 3) * 16 + vj];
        } else {
            s1_0 = Kb4[(KVT + srow) * 16 + sslot * 2];
            s1_1 = Kb4[(KVT + srow) * 16 + sslot * 2 + 1];
            s1_2 = Kb4[(KVT + srow + 32) * 16 + sslot * 2];
            s1_3 = Kb4[(KVT + srow + 32) * 16 + sslot * 2 + 1];
        }
    }
    store_kv(0);                           // waits set A; set B still flying
    if (nt > 1) store_from(1, s1_0, s1_1, s1_2, s1_3);

    // ---- main loop: ONE barrier per tile PAIR; bufs cycle 0,1,2,3 ----
    for (int t = 0; t < nt; t += 4) {
        __syncthreads();                       // bufs {0,1} ready; {2,3} free
        if (t + 2 < nt) load_kv((t + 2) * KVT);
        __builtin_amdgcn_sched_barrier(0);
        compute_tile(t, 0);
        if (t + 2 < nt) store_kv(2);
        if (t + 3 < nt) load_kv((t + 3) * KVT);
        __builtin_amdgcn_sched_barrier(0);
        if (t + 1 < nt) compute_tile(t + 1, 1);
        if (t + 3 < nt) store_kv(3);
        if (t + 2 < nt) {
            __syncthreads();                   // bufs {2,3} ready; {0,1} free
            if (t + 4 < nt) load_kv((t + 4) * KVT);
            __builtin_amdgcn_sched_barrier(0);
            compute_tile(t + 2, 2);
            if (t + 4 < nt) store_kv(0);
            if (t + 5 < nt) load_kv((t + 5) * KVT);
            __builtin_amdgcn_sched_barrier(0);
            if (t + 3 < nt) compute_tile(t + 3, 3);
            if (t + 5 < nt) store_kv(1);
        }
    }

    // ---- epilogue: O[q=4g+r][d=16n+a] / l (lacc already row-layout) ----
    float iv[4];
    #pragma unroll
    for (int r = 0; r < 4; ++r) iv[r] = 1.0f / lacc[r];
    float* Ob = O + ((size_t)b * LQ + qbase + wid * 16) * DH;
    #pragma unroll
    for (int n = 0; n < 4; ++n)
        #pragma unroll
        for (int r = 0; r < 4; ++r)
            Ob[(size_t)(4 * g + r) * DH + 16 * n + a] = oacc[n][r] * iv[r];
}

extern "C" void kernel_launch(void* const* d_in, const int* in_sizes, int n_in,
                              void* d_out, int out_size, void* d_ws, size_t ws_size,
                              hipStream_t stream) {
    const float* Q  = (const float*)d_in[0];
    const float* K  = (const float*)d_in[1];
    const float* V  = (const float*)d_in[2];
    const int*   VL = (const int*)d_in[3];
    float* O = (float*)d_out;

    attn_v28<<<NITEMS, 512, 0, stream>>>(Q, K, V, VL, O);
}